// Round 12
// baseline (155.912 us; speedup 1.0000x reference)
//
#include <hip/hip_runtime.h>
#include <hip/hip_bf16.h>
#include <hip/hip_fp16.h>
#include <math.h>

typedef short s16x8 __attribute__((ext_vector_type(8)));
typedef float f32x4 __attribute__((ext_vector_type(4)));
typedef float f32x16 __attribute__((ext_vector_type(16)));
typedef unsigned short u16x4 __attribute__((ext_vector_type(4)));
typedef unsigned short u16x8 __attribute__((ext_vector_type(8)));
typedef unsigned int u32x4 __attribute__((ext_vector_type(4)));

#define CCH 256
#define SEQ 4096
#define NB 4
#define KVB 64

static __device__ __forceinline__ unsigned short f2bf(float f) {
  union { float f; unsigned int u; } v; v.f = f;
  unsigned int u = v.u;
  unsigned int r = u + 0x7FFFu + ((u >> 16) & 1u);   // RNE
  return (unsigned short)(r >> 16);
}

static __device__ __forceinline__ void gl16(const void* g, void* l) {
  __builtin_amdgcn_global_load_lds(
      (const __attribute__((address_space(1))) void*)g,
      (__attribute__((address_space(3))) void*)l, 16, 0, 0);
}

static __device__ __forceinline__ unsigned int cvt_pk_bf16(float lo, float hi) {
  unsigned int w;
  asm("v_cvt_pk_bf16_f32 %0, %1, %2" : "=v"(w) : "v"(lo), "v"(hi));
  return w;
}

// ---------------- prep: weight matrices fp32 -> bf16 only ----------------
__global__ __launch_bounds__(256) void prep(
    const float* __restrict__ wqkv, const float* __restrict__ wout,
    unsigned short* __restrict__ wqkb, unsigned short* __restrict__ wob)
{
  int bid = blockIdx.x;
  int tid = threadIdx.x;
  const float* src; unsigned short* dst; int i;
  if (bid < 192) { src = wqkv; dst = wqkb; i = bid * 256 + tid; }
  else           { src = wout; dst = wob;  i = (bid - 192) * 256 + tid; }
  float4 v = ((const float4*)src)[i];
  u16x4 r;
  r.x = f2bf(v.x); r.y = f2bf(v.y); r.z = f2bf(v.z); r.w = f2bf(v.w);
  ((u16x4*)dst)[i] = r;
}

// ---------------- qkv_proj: in-kernel x transpose (round-11 proven) ----------------
__global__ __launch_bounds__(512) void qkv_proj(
    const float* __restrict__ x, const unsigned short* __restrict__ wqkb,
    const float* __restrict__ bias,
    unsigned short* __restrict__ qb, unsigned short* __restrict__ kb,
    unsigned short* __restrict__ vb)
{
  __shared__ __align__(16) unsigned short T[32][256];   // 16KB, chunk c16 ^= (s&7)
  int b = blockIdx.y, st = blockIdx.x;   // st 0..127
  int tid = threadIdx.x, w = tid >> 6, l = tid & 63, l15 = l & 15, lg = l >> 4;
  int sbase = st * 32;
  int s7 = l15 & 7;

  #pragma unroll
  for (int i = 0; i < 4; i++) {
    int idx = i * 512 + tid;
    int sc = idx & 7, ch = idx >> 3;
    float4 v = *(const float4*)&x[((size_t)b * CCH + ch) * SEQ + sbase + sc * 4];
    #pragma unroll
    for (int j = 0; j < 4; j++) {
      int s = sc * 4 + j;
      int csw = (((ch >> 3) ^ (s & 7)) << 3) | (ch & 7);
      float fv = (j == 0) ? v.x : (j == 1) ? v.y : (j == 2) ? v.z : v.w;
      T[s][csw] = f2bf(fv);
    }
  }
  __syncthreads();

  if (w < 4) {
    int sloc = (w & 1) * 16;
    int row0 = sbase + sloc;
    int osel = w >> 1;
    s16x8 af[8];
    #pragma unroll
    for (int t = 0; t < 8; t++)
      af[t] = *(const s16x8*)&T[sloc + l15][(((t * 4 + lg) ^ s7)) * 8];

    unsigned short* dst = osel ? kb : qb;
    #pragma unroll
    for (int ot = 0; ot < 16; ot++) {
      int orow = osel * 256 + ot * 16;
      f32x4 acc = (f32x4){0.f, 0.f, 0.f, 0.f};
      #pragma unroll
      for (int t = 0; t < 8; t++) {
        s16x8 wf = *(const s16x8*)&wqkb[(size_t)(orow + l15) * CCH + t * 32 + lg * 8];
        acc = __builtin_amdgcn_mfma_f32_16x16x32_bf16(af[t], wf, acc, 0, 0, 0);
      }
      float bi = bias[orow + l15];
      int ch = ot * 16 + l15;
      #pragma unroll
      for (int r = 0; r < 4; r++) {
        int srow = row0 + lg * 4 + r;
        dst[((size_t)b * SEQ + srow) * CCH + ch] = f2bf(acc[r] + bi);
      }
    }
  } else {
    int obase = (w - 4) * 64;
    f32x4 acc[4][2];
    #pragma unroll
    for (int i = 0; i < 4; i++)
      #pragma unroll
      for (int j = 0; j < 2; j++) acc[i][j] = (f32x4){0.f, 0.f, 0.f, 0.f};

    #pragma unroll
    for (int kt = 0; kt < 8; kt++) {
      s16x8 afr[4], bfr[2];
      #pragma unroll
      for (int ot = 0; ot < 4; ot++)
        afr[ot] = *(const s16x8*)&wqkb[(size_t)(512 + obase + ot * 16 + l15) * CCH + kt * 32 + lg * 8];
      #pragma unroll
      for (int sj = 0; sj < 2; sj++)
        bfr[sj] = *(const s16x8*)&T[sj * 16 + l15][(((kt * 4 + lg) ^ s7)) * 8];
      #pragma unroll
      for (int ot = 0; ot < 4; ot++)
        #pragma unroll
        for (int sj = 0; sj < 2; sj++)
          acc[ot][sj] = __builtin_amdgcn_mfma_f32_16x16x32_bf16(afr[ot], bfr[sj], acc[ot][sj], 0, 0, 0);
    }

    #pragma unroll
    for (int ot = 0; ot < 4; ot++) {
      #pragma unroll
      for (int r = 0; r < 4; r++) {
        int o = obase + ot * 16 + lg * 4 + r;
        float bi = bias[512 + o];
        #pragma unroll
        for (int sj = 0; sj < 2; sj++) {
          int s = sbase + sj * 16 + l15;
          vb[((size_t)b * CCH + o) * SEQ + s] = f2bf(acc[ot][sj][r] + bi);
        }
      }
    }
  }
}

// ---------------- attn: software-pipelined halves: QK0,SM0,[QK1||PV0],SM1,PV1 --------
// Swapped QK^T: sacc = mfma(K, Q) -> D[key][q]; C/D layout (verified):
// col = lane&31, row = (reg&3) + 8*(reg>>2) + 4*(lane>>5).
template<int NSPLIT_>
__global__ __launch_bounds__(512, 2) void attn_kernel(
    const unsigned short* __restrict__ qb,
    const unsigned short* __restrict__ kb,
    const unsigned short* __restrict__ vb,
    __half* __restrict__ pacc, float* __restrict__ llp)
{
  constexpr int KVLEN_ = SEQ / NSPLIT_;
  constexpr int NT_ = KVLEN_ / KVB;
  __shared__ __align__(16) unsigned short Ks[2][KVB * CCH];   // 2 x 32KB
  __shared__ __align__(16) unsigned short Vs[2][CCH * KVB];   // 2 x 32KB

  int b = blockIdx.z, kvh = blockIdx.y, qt = blockIdx.x;
  int tid = threadIdx.x, w = tid >> 6, l = tid & 63;
  int l31 = l & 31, lh = l >> 5;
  int s7 = l31 & 7;

  int qrow0 = qt * 256 + w * 32;
  const unsigned short* qptr = qb + ((size_t)b * SEQ + qrow0 + l31) * CCH + lh * 8;
  s16x8 qf[16];
  #pragma unroll
  for (int t = 0; t < 16; t++) qf[t] = *(const s16x8*)(qptr + t * 16);

  f32x16 oacc[8];
  #pragma unroll
  for (int i = 0; i < 8; i++)
    #pragma unroll
    for (int j = 0; j < 16; j++) oacc[i][j] = 0.f;
  float ll = 0.f;

  int koff0 = (tid >> 5) * CCH + (((tid & 31) ^ ((tid >> 5) & 7)) * 8);
  int voff0 = (tid >> 3) * SEQ + (((tid & 7) ^ ((tid >> 3) & 7)) * 8);
  const unsigned short* kbb = kb + (size_t)b * SEQ * CCH + (size_t)kvh * KVLEN_ * CCH;
  const unsigned short* vbb = vb + (size_t)b * CCH * SEQ + kvh * KVLEN_;

  auto stage = [&](int bf_, int kv) {
    #pragma unroll
    for (int i = 0; i < 4; i++)
      gl16(kbb + (size_t)kv * KVB * CCH + koff0 + i * 16 * CCH, &Ks[bf_][(i * 512 + tid) * 8]);
    #pragma unroll
    for (int i = 0; i < 4; i++)
      gl16(vbb + kv * KVB + voff0 + (size_t)i * 64 * SEQ, &Vs[bf_][(i * 512 + tid) * 8]);
  };

  stage(0, 0);
  __syncthreads();

  int buf = 0;
  for (int kv = 0; kv < NT_; kv++) {
    if (kv + 1 < NT_) stage(buf ^ 1, kv + 1);

    const unsigned short* Kb = &Ks[buf][0];
    const unsigned short* Vb = &Vs[buf][0];

    // ---- Phase A: QK half 0 ----
    f32x16 sacc0;
    #pragma unroll
    for (int i = 0; i < 16; i++) sacc0[i] = 0.f;
    __builtin_amdgcn_s_setprio(1);
    #pragma unroll
    for (int st = 0; st < 16; st++) {
      s16x8 kf = *(const s16x8*)&Kb[l31 * CCH + (((st * 2 + lh) ^ s7) * 8)];
      sacc0 = __builtin_amdgcn_mfma_f32_32x32x16_bf16(kf, qf[st], sacc0, 0, 0, 0);
    }
    __builtin_amdgcn_s_setprio(0);

    // ---- SM0: fixed-shift softmax + in-register P->A-frag ----
    unsigned int pw0[8];
    #pragma unroll
    for (int r = 0; r < 8; r++) {
      float p0 = __builtin_amdgcn_exp2f(fmaf(sacc0[2 * r],     0.09016844f, -11.5415602f));
      float p1 = __builtin_amdgcn_exp2f(fmaf(sacc0[2 * r + 1], 0.09016844f, -11.5415602f));
      ll += p0 + p1;
      pw0[r] = cvt_pk_bf16(p0, p1);
    }
    asm volatile("v_permlane32_swap_b32 %0, %1" : "+v"(pw0[0]), "+v"(pw0[2]));
    asm volatile("v_permlane32_swap_b32 %0, %1" : "+v"(pw0[1]), "+v"(pw0[3]));
    asm volatile("v_permlane32_swap_b32 %0, %1" : "+v"(pw0[4]), "+v"(pw0[6]));
    asm volatile("v_permlane32_swap_b32 %0, %1" : "+v"(pw0[5]), "+v"(pw0[7]));
    u32x4 pa00u = {pw0[0], pw0[1], pw0[2], pw0[3]};
    u32x4 pa01u = {pw0[4], pw0[5], pw0[6], pw0[7]};
    s16x8 pa00 = *(s16x8*)&pa00u;
    s16x8 pa01 = *(s16x8*)&pa01u;

    // ---- Phase B: QK half 1 interleaved 1:1 with PV half 0 (independent chains) ----
    f32x16 sacc1;
    #pragma unroll
    for (int i = 0; i < 16; i++) sacc1[i] = 0.f;
    __builtin_amdgcn_s_setprio(1);
    #pragma unroll
    for (int i = 0; i < 8; i++) {
      int base = (i * 32 + l31) * KVB;
      s16x8 kfa = *(const s16x8*)&Kb[(32 + l31) * CCH + (((4 * i + lh) ^ s7) * 8)];
      sacc1 = __builtin_amdgcn_mfma_f32_32x32x16_bf16(kfa, qf[2 * i], sacc1, 0, 0, 0);
      s16x8 vf0 = *(const s16x8*)&Vb[base + ((lh ^ s7) * 8)];
      oacc[i] = __builtin_amdgcn_mfma_f32_32x32x16_bf16(pa00, vf0, oacc[i], 0, 0, 0);
      s16x8 kfb = *(const s16x8*)&Kb[(32 + l31) * CCH + (((4 * i + 2 + lh) ^ s7) * 8)];
      sacc1 = __builtin_amdgcn_mfma_f32_32x32x16_bf16(kfb, qf[2 * i + 1], sacc1, 0, 0, 0);
      s16x8 vf1 = *(const s16x8*)&Vb[base + (((2 + lh) ^ s7) * 8)];
      oacc[i] = __builtin_amdgcn_mfma_f32_32x32x16_bf16(pa01, vf1, oacc[i], 0, 0, 0);
    }
    __builtin_amdgcn_s_setprio(0);

    // ---- SM1 ----
    unsigned int pw1[8];
    #pragma unroll
    for (int r = 0; r < 8; r++) {
      float p0 = __builtin_amdgcn_exp2f(fmaf(sacc1[2 * r],     0.09016844f, -11.5415602f));
      float p1 = __builtin_amdgcn_exp2f(fmaf(sacc1[2 * r + 1], 0.09016844f, -11.5415602f));
      ll += p0 + p1;
      pw1[r] = cvt_pk_bf16(p0, p1);
    }
    asm volatile("v_permlane32_swap_b32 %0, %1" : "+v"(pw1[0]), "+v"(pw1[2]));
    asm volatile("v_permlane32_swap_b32 %0, %1" : "+v"(pw1[1]), "+v"(pw1[3]));
    asm volatile("v_permlane32_swap_b32 %0, %1" : "+v"(pw1[4]), "+v"(pw1[6]));
    asm volatile("v_permlane32_swap_b32 %0, %1" : "+v"(pw1[5]), "+v"(pw1[7]));
    u32x4 pa10u = {pw1[0], pw1[1], pw1[2], pw1[3]};
    u32x4 pa11u = {pw1[4], pw1[5], pw1[6], pw1[7]};
    s16x8 pa10 = *(s16x8*)&pa10u;
    s16x8 pa11 = *(s16x8*)&pa11u;

    // ---- Phase C: PV half 1 ----
    __builtin_amdgcn_s_setprio(1);
    #pragma unroll
    for (int dt = 0; dt < 8; dt++) {
      int base = (dt * 32 + l31) * KVB;
      s16x8 vf0 = *(const s16x8*)&Vb[base + (((4 + lh) ^ s7) * 8)];
      oacc[dt] = __builtin_amdgcn_mfma_f32_32x32x16_bf16(pa10, vf0, oacc[dt], 0, 0, 0);
      s16x8 vf1 = *(const s16x8*)&Vb[base + (((6 + lh) ^ s7) * 8)];
      oacc[dt] = __builtin_amdgcn_mfma_f32_32x32x16_bf16(pa11, vf1, oacc[dt], 0, 0, 0);
    }
    __builtin_amdgcn_s_setprio(0);

    __syncthreads();
    buf ^= 1;
  }

  // ---- epilogue ----
  ll += __shfl_xor(ll, 32);
  size_t pbase = (size_t)(b * NSPLIT_ + kvh) * SEQ;
  if (lh == 0) llp[pbase + qrow0 + l31] = ll;
  __half* pb_ = pacc + (pbase + qrow0) * CCH + l31;
  #pragma unroll
  for (int rg = 0; rg < 4; rg++)
    #pragma unroll
    for (int j = 0; j < 4; j++) {
      int qr = j + 8 * rg + 4 * lh;
      #pragma unroll
      for (int dt = 0; dt < 8; dt++)
        pb_[(size_t)qr * CCH + dt * 32] = __float2half(oacc[dt][rg * 4 + j]);
    }
}

// ---------------- out_proj fused with combine; normalization deferred to epilogue ----
template<int NS>
__global__ __launch_bounds__(256) void out_proj(
    const __half* __restrict__ pacc, const float* __restrict__ llp,
    const unsigned short* __restrict__ wb,
    const float* __restrict__ bias, const float* __restrict__ x,
    float* __restrict__ out)
{
  int b = blockIdx.y, st = blockIdx.x;   // st 0..127
  int tid = threadIdx.x, w = tid >> 6, l = tid & 63, l15 = l & 15, lg = l >> 4;
  int sbase = st * 32, obase = w * 64;

  float inv[2];
  #pragma unroll
  for (int sj = 0; sj < 2; sj++) {
    int s = sbase + sj * 16 + l15;
    float den = 0.f;
    #pragma unroll
    for (int k = 0; k < NS; k++) den += llp[(size_t)(b * NS + k) * SEQ + s];
    inv[sj] = 1.f / den;
  }

  f32x4 acc[4][2];
  #pragma unroll
  for (int i = 0; i < 4; i++)
    #pragma unroll
    for (int j = 0; j < 2; j++) acc[i][j] = (f32x4){0.f, 0.f, 0.f, 0.f};

  #pragma unroll
  for (int kt = 0; kt < 8; kt++) {
    s16x8 af[4], bfr[2];
    #pragma unroll
    for (int ot = 0; ot < 4; ot++)
      af[ot] = *(const s16x8*)&wb[(obase + ot * 16 + l15) * CCH + kt * 32 + lg * 8];
    #pragma unroll
    for (int sj = 0; sj < 2; sj++) {
      int s = sbase + sj * 16 + l15;
      float facc[8] = {0.f, 0.f, 0.f, 0.f, 0.f, 0.f, 0.f, 0.f};
      #pragma unroll
      for (int k = 0; k < NS; k++) {
        const __half* p = pacc + ((size_t)(b * NS + k) * SEQ + s) * CCH + kt * 32 + lg * 8;
        u16x8 h8 = *(const u16x8*)(p);
        #pragma unroll
        for (int j = 0; j < 8; j++)
          facc[j] += __half2float(*(const __half*)&((const unsigned short*)&h8)[j]);
      }
      unsigned short tmp[8];
      #pragma unroll
      for (int j = 0; j < 8; j++) tmp[j] = f2bf(facc[j]);   // raw sums; normalize later
      bfr[sj] = *(s16x8*)tmp;
    }
    #pragma unroll
    for (int ot = 0; ot < 4; ot++)
      #pragma unroll
      for (int sj = 0; sj < 2; sj++)
        acc[ot][sj] = __builtin_amdgcn_mfma_f32_16x16x32_bf16(af[ot], bfr[sj], acc[ot][sj], 0, 0, 0);
  }

  #pragma unroll
  for (int ot = 0; ot < 4; ot++) {
    #pragma unroll
    for (int r = 0; r < 4; r++) {
      int o = obase + ot * 16 + lg * 4 + r;
      float bi = bias[o];
      #pragma unroll
      for (int sj = 0; sj < 2; sj++) {
        int s = sbase + sj * 16 + l15;
        size_t idx = ((size_t)b * CCH + o) * SEQ + s;
        out[idx] = acc[ot][sj][r] * inv[sj] + bi + x[idx];
      }
    }
  }
}

extern "C" void kernel_launch(void* const* d_in, const int* in_sizes, int n_in,
                              void* d_out, int out_size, void* d_ws, size_t ws_size,
                              hipStream_t stream) {
  const float* x     = (const float*)d_in[0];
  const float* w_qkv = (const float*)d_in[1];
  const float* b_qkv = (const float*)d_in[2];
  const float* w_out = (const float*)d_in[3];
  const float* b_out = (const float*)d_in[4];
  float* out = (float*)d_out;

  // ws: qb 0 | kb 8 | vb 16 | wqkb 24 | wob 24.5 | llp 25 | pacc 26.. (split4 ends 59.6)
  char* ws = (char*)d_ws;
  unsigned short* qbp  = (unsigned short*)(ws);
  unsigned short* kbp  = (unsigned short*)(ws + ((size_t)8 << 20));
  unsigned short* vbp  = (unsigned short*)(ws + ((size_t)16 << 20));
  unsigned short* wqkb = (unsigned short*)(ws + ((size_t)24 << 20));
  unsigned short* wob  = (unsigned short*)(ws + ((size_t)24 << 20) + (512u << 10));
  float*          llp  = (float*)(ws + ((size_t)25 << 20));
  __half*         pacc = (__half*)(ws + ((size_t)26 << 20));

  prep<<<dim3(256), 256, 0, stream>>>(w_qkv, w_out, wqkb, wob);
  qkv_proj<<<dim3(128, NB), 512, 0, stream>>>(x, wqkb, b_qkv, qbp, kbp, vbp);

  bool split4 = ws_size >= ((size_t)60 << 20);
  if (split4) {
    attn_kernel<4><<<dim3(16, 4, NB), 512, 0, stream>>>(qbp, kbp, vbp, pacc, llp);
    out_proj<4><<<dim3(128, NB), 256, 0, stream>>>(pacc, llp, wob, b_out, x, out);
  } else {
    attn_kernel<2><<<dim3(16, 2, NB), 512, 0, stream>>>(qbp, kbp, vbp, pacc, llp);
    out_proj<2><<<dim3(128, NB), 256, 0, stream>>>(pacc, llp, wob, b_out, x, out);
  }
}

// Round 13
// 150.635 us; speedup vs baseline: 1.0350x; 1.0350x over previous
//
#include <hip/hip_runtime.h>
#include <hip/hip_bf16.h>
#include <hip/hip_fp16.h>
#include <math.h>

typedef short s16x8 __attribute__((ext_vector_type(8)));
typedef float f32x4 __attribute__((ext_vector_type(4)));
typedef float f32x16 __attribute__((ext_vector_type(16)));
typedef unsigned short u16x4 __attribute__((ext_vector_type(4)));
typedef unsigned short u16x8 __attribute__((ext_vector_type(8)));
typedef unsigned int u32x4 __attribute__((ext_vector_type(4)));

#define CCH 256
#define SEQ 4096
#define NB 4
#define KVB 64

static __device__ __forceinline__ unsigned short f2bf(float f) {
  union { float f; unsigned int u; } v; v.f = f;
  unsigned int u = v.u;
  unsigned int r = u + 0x7FFFu + ((u >> 16) & 1u);   // RNE
  return (unsigned short)(r >> 16);
}

static __device__ __forceinline__ void gl16(const void* g, void* l) {
  __builtin_amdgcn_global_load_lds(
      (const __attribute__((address_space(1))) void*)g,
      (__attribute__((address_space(3))) void*)l, 16, 0, 0);
}

static __device__ __forceinline__ unsigned int cvt_pk_bf16(float lo, float hi) {
  unsigned int w;
  asm("v_cvt_pk_bf16_f32 %0, %1, %2" : "=v"(w) : "v"(lo), "v"(hi));
  return w;
}

// ---------------- prep: weight matrices fp32 -> bf16 only ----------------
__global__ __launch_bounds__(256) void prep(
    const float* __restrict__ wqkv, const float* __restrict__ wout,
    unsigned short* __restrict__ wqkb, unsigned short* __restrict__ wob)
{
  int bid = blockIdx.x;
  int tid = threadIdx.x;
  const float* src; unsigned short* dst; int i;
  if (bid < 192) { src = wqkv; dst = wqkb; i = bid * 256 + tid; }
  else           { src = wout; dst = wob;  i = (bid - 192) * 256 + tid; }
  float4 v = ((const float4*)src)[i];
  u16x4 r;
  r.x = f2bf(v.x); r.y = f2bf(v.y); r.z = f2bf(v.z); r.w = f2bf(v.w);
  ((u16x4*)dst)[i] = r;
}

// ---------------- qkv_proj: in-kernel x transpose (round-11 proven) ----------------
__global__ __launch_bounds__(512) void qkv_proj(
    const float* __restrict__ x, const unsigned short* __restrict__ wqkb,
    const float* __restrict__ bias,
    unsigned short* __restrict__ qb, unsigned short* __restrict__ kb,
    unsigned short* __restrict__ vb)
{
  __shared__ __align__(16) unsigned short T[32][256];   // 16KB, chunk c16 ^= (s&7)
  int b = blockIdx.y, st = blockIdx.x;   // st 0..127
  int tid = threadIdx.x, w = tid >> 6, l = tid & 63, l15 = l & 15, lg = l >> 4;
  int sbase = st * 32;
  int s7 = l15 & 7;

  #pragma unroll
  for (int i = 0; i < 4; i++) {
    int idx = i * 512 + tid;
    int sc = idx & 7, ch = idx >> 3;
    float4 v = *(const float4*)&x[((size_t)b * CCH + ch) * SEQ + sbase + sc * 4];
    #pragma unroll
    for (int j = 0; j < 4; j++) {
      int s = sc * 4 + j;
      int csw = (((ch >> 3) ^ (s & 7)) << 3) | (ch & 7);
      float fv = (j == 0) ? v.x : (j == 1) ? v.y : (j == 2) ? v.z : v.w;
      T[s][csw] = f2bf(fv);
    }
  }
  __syncthreads();

  if (w < 4) {
    int sloc = (w & 1) * 16;
    int row0 = sbase + sloc;
    int osel = w >> 1;
    s16x8 af[8];
    #pragma unroll
    for (int t = 0; t < 8; t++)
      af[t] = *(const s16x8*)&T[sloc + l15][(((t * 4 + lg) ^ s7)) * 8];

    unsigned short* dst = osel ? kb : qb;
    #pragma unroll
    for (int ot = 0; ot < 16; ot++) {
      int orow = osel * 256 + ot * 16;
      f32x4 acc = (f32x4){0.f, 0.f, 0.f, 0.f};
      #pragma unroll
      for (int t = 0; t < 8; t++) {
        s16x8 wf = *(const s16x8*)&wqkb[(size_t)(orow + l15) * CCH + t * 32 + lg * 8];
        acc = __builtin_amdgcn_mfma_f32_16x16x32_bf16(af[t], wf, acc, 0, 0, 0);
      }
      float bi = bias[orow + l15];
      int ch = ot * 16 + l15;
      #pragma unroll
      for (int r = 0; r < 4; r++) {
        int srow = row0 + lg * 4 + r;
        dst[((size_t)b * SEQ + srow) * CCH + ch] = f2bf(acc[r] + bi);
      }
    }
  } else {
    int obase = (w - 4) * 64;
    f32x4 acc[4][2];
    #pragma unroll
    for (int i = 0; i < 4; i++)
      #pragma unroll
      for (int j = 0; j < 2; j++) acc[i][j] = (f32x4){0.f, 0.f, 0.f, 0.f};

    #pragma unroll
    for (int kt = 0; kt < 8; kt++) {
      s16x8 afr[4], bfr[2];
      #pragma unroll
      for (int ot = 0; ot < 4; ot++)
        afr[ot] = *(const s16x8*)&wqkb[(size_t)(512 + obase + ot * 16 + l15) * CCH + kt * 32 + lg * 8];
      #pragma unroll
      for (int sj = 0; sj < 2; sj++)
        bfr[sj] = *(const s16x8*)&T[sj * 16 + l15][(((kt * 4 + lg) ^ s7)) * 8];
      #pragma unroll
      for (int ot = 0; ot < 4; ot++)
        #pragma unroll
        for (int sj = 0; sj < 2; sj++)
          acc[ot][sj] = __builtin_amdgcn_mfma_f32_16x16x32_bf16(afr[ot], bfr[sj], acc[ot][sj], 0, 0, 0);
    }

    #pragma unroll
    for (int ot = 0; ot < 4; ot++) {
      #pragma unroll
      for (int r = 0; r < 4; r++) {
        int o = obase + ot * 16 + lg * 4 + r;
        float bi = bias[512 + o];
        #pragma unroll
        for (int sj = 0; sj < 2; sj++) {
          int s = sbase + sj * 16 + l15;
          vb[((size_t)b * CCH + o) * SEQ + s] = f2bf(acc[ot][sj][r] + bi);
        }
      }
    }
  }
}

// ---------------- attn: 32x32x16, KVB=64, in-reg P (round-10/11 proven, reverted) ----
// Swapped QK^T: sacc = mfma(K, Q) -> D[key][q]; C/D layout (verified):
// col = lane&31, row = (reg&3) + 8*(reg>>2) + 4*(lane>>5).
// s7-only LDS swizzle: PV V-addresses stay dt-invariant -> immediate-offset ds_reads.
template<int NSPLIT_>
__global__ __launch_bounds__(512, 2) void attn_kernel(
    const unsigned short* __restrict__ qb,
    const unsigned short* __restrict__ kb,
    const unsigned short* __restrict__ vb,
    __half* __restrict__ pacc, float* __restrict__ llp)
{
  constexpr int KVLEN_ = SEQ / NSPLIT_;
  constexpr int NT_ = KVLEN_ / KVB;
  __shared__ __align__(16) unsigned short Ks[2][KVB * CCH];   // 2 x 32KB
  __shared__ __align__(16) unsigned short Vs[2][CCH * KVB];   // 2 x 32KB

  int b = blockIdx.z, kvh = blockIdx.y, qt = blockIdx.x;
  int tid = threadIdx.x, w = tid >> 6, l = tid & 63;
  int l31 = l & 31, lh = l >> 5;
  int s7 = l31 & 7;

  int qrow0 = qt * 256 + w * 32;
  const unsigned short* qptr = qb + ((size_t)b * SEQ + qrow0 + l31) * CCH + lh * 8;
  s16x8 qf[16];
  #pragma unroll
  for (int t = 0; t < 16; t++) qf[t] = *(const s16x8*)(qptr + t * 16);

  f32x16 oacc[8];
  #pragma unroll
  for (int i = 0; i < 8; i++)
    #pragma unroll
    for (int j = 0; j < 16; j++) oacc[i][j] = 0.f;
  float ll = 0.f;

  int koff0 = (tid >> 5) * CCH + (((tid & 31) ^ ((tid >> 5) & 7)) * 8);
  int voff0 = (tid >> 3) * SEQ + (((tid & 7) ^ ((tid >> 3) & 7)) * 8);
  const unsigned short* kbb = kb + (size_t)b * SEQ * CCH + (size_t)kvh * KVLEN_ * CCH;
  const unsigned short* vbb = vb + (size_t)b * CCH * SEQ + kvh * KVLEN_;

  auto stage = [&](int bf_, int kv) {
    #pragma unroll
    for (int i = 0; i < 4; i++)
      gl16(kbb + (size_t)kv * KVB * CCH + koff0 + i * 16 * CCH, &Ks[bf_][(i * 512 + tid) * 8]);
    #pragma unroll
    for (int i = 0; i < 4; i++)
      gl16(vbb + kv * KVB + voff0 + (size_t)i * 64 * SEQ, &Vs[bf_][(i * 512 + tid) * 8]);
  };

  stage(0, 0);
  __syncthreads();

  int buf = 0;
  for (int kv = 0; kv < NT_; kv++) {
    if (kv + 1 < NT_) stage(buf ^ 1, kv + 1);

    #pragma unroll
    for (int h = 0; h < 2; h++) {
      f32x16 sacc;
      #pragma unroll
      for (int i = 0; i < 16; i++) sacc[i] = 0.f;
      __builtin_amdgcn_s_setprio(1);
      #pragma unroll
      for (int st = 0; st < 16; st++) {
        s16x8 kf = *(const s16x8*)&Ks[buf][(h * 32 + l31) * CCH + (((st * 2 + lh) ^ s7) * 8)];
        sacc = __builtin_amdgcn_mfma_f32_32x32x16_bf16(kf, qf[st], sacc, 0, 0, 0);
      }
      __builtin_amdgcn_s_setprio(0);

      unsigned int pw[8];
      #pragma unroll
      for (int r = 0; r < 8; r++) {
        float p0 = __builtin_amdgcn_exp2f(fmaf(sacc[2 * r],     0.09016844f, -11.5415602f));
        float p1 = __builtin_amdgcn_exp2f(fmaf(sacc[2 * r + 1], 0.09016844f, -11.5415602f));
        ll += p0 + p1;
        pw[r] = cvt_pk_bf16(p0, p1);
      }
      asm volatile("v_permlane32_swap_b32 %0, %1" : "+v"(pw[0]), "+v"(pw[2]));
      asm volatile("v_permlane32_swap_b32 %0, %1" : "+v"(pw[1]), "+v"(pw[3]));
      asm volatile("v_permlane32_swap_b32 %0, %1" : "+v"(pw[4]), "+v"(pw[6]));
      asm volatile("v_permlane32_swap_b32 %0, %1" : "+v"(pw[5]), "+v"(pw[7]));
      u32x4 pa0u = {pw[0], pw[1], pw[2], pw[3]};   // keys h*32 + 0..15
      u32x4 pa1u = {pw[4], pw[5], pw[6], pw[7]};   // keys h*32 + 16..31
      s16x8 pa0 = *(s16x8*)&pa0u;
      s16x8 pa1 = *(s16x8*)&pa1u;

      __builtin_amdgcn_s_setprio(1);
      #pragma unroll
      for (int dt = 0; dt < 8; dt++) {
        int base = (dt * 32 + l31) * KVB;
        s16x8 vf0 = *(const s16x8*)&Vs[buf][base + (((h * 4 + lh) ^ s7) * 8)];
        oacc[dt] = __builtin_amdgcn_mfma_f32_32x32x16_bf16(pa0, vf0, oacc[dt], 0, 0, 0);
        s16x8 vf1 = *(const s16x8*)&Vs[buf][base + (((h * 4 + 2 + lh) ^ s7) * 8)];
        oacc[dt] = __builtin_amdgcn_mfma_f32_32x32x16_bf16(pa1, vf1, oacc[dt], 0, 0, 0);
      }
      __builtin_amdgcn_s_setprio(0);
    }

    __syncthreads();
    buf ^= 1;
  }

  ll += __shfl_xor(ll, 32);
  size_t pbase = (size_t)(b * NSPLIT_ + kvh) * SEQ;
  if (lh == 0) llp[pbase + qrow0 + l31] = ll;
  __half* pb_ = pacc + (pbase + qrow0) * CCH + l31;
  #pragma unroll
  for (int rg = 0; rg < 4; rg++)
    #pragma unroll
    for (int j = 0; j < 4; j++) {
      int qr = j + 8 * rg + 4 * lh;
      #pragma unroll
      for (int dt = 0; dt < 8; dt++)
        pb_[(size_t)qr * CCH + dt * 32] = __float2half(oacc[dt][rg * 4 + j]);
    }
}

// ---------------- out_proj fused with combine; deferred normalization (round-12) ----
template<int NS>
__global__ __launch_bounds__(256) void out_proj(
    const __half* __restrict__ pacc, const float* __restrict__ llp,
    const unsigned short* __restrict__ wb,
    const float* __restrict__ bias, const float* __restrict__ x,
    float* __restrict__ out)
{
  int b = blockIdx.y, st = blockIdx.x;   // st 0..127
  int tid = threadIdx.x, w = tid >> 6, l = tid & 63, l15 = l & 15, lg = l >> 4;
  int sbase = st * 32, obase = w * 64;

  float inv[2];
  #pragma unroll
  for (int sj = 0; sj < 2; sj++) {
    int s = sbase + sj * 16 + l15;
    float den = 0.f;
    #pragma unroll
    for (int k = 0; k < NS; k++) den += llp[(size_t)(b * NS + k) * SEQ + s];
    inv[sj] = 1.f / den;
  }

  f32x4 acc[4][2];
  #pragma unroll
  for (int i = 0; i < 4; i++)
    #pragma unroll
    for (int j = 0; j < 2; j++) acc[i][j] = (f32x4){0.f, 0.f, 0.f, 0.f};

  #pragma unroll
  for (int kt = 0; kt < 8; kt++) {
    s16x8 af[4], bfr[2];
    #pragma unroll
    for (int ot = 0; ot < 4; ot++)
      af[ot] = *(const s16x8*)&wb[(obase + ot * 16 + l15) * CCH + kt * 32 + lg * 8];
    #pragma unroll
    for (int sj = 0; sj < 2; sj++) {
      int s = sbase + sj * 16 + l15;
      float facc[8] = {0.f, 0.f, 0.f, 0.f, 0.f, 0.f, 0.f, 0.f};
      #pragma unroll
      for (int k = 0; k < NS; k++) {
        const __half* p = pacc + ((size_t)(b * NS + k) * SEQ + s) * CCH + kt * 32 + lg * 8;
        u16x8 h8 = *(const u16x8*)(p);
        #pragma unroll
        for (int j = 0; j < 8; j++)
          facc[j] += __half2float(*(const __half*)&((const unsigned short*)&h8)[j]);
      }
      unsigned short tmp[8];
      #pragma unroll
      for (int j = 0; j < 8; j++) tmp[j] = f2bf(facc[j]);   // raw sums; normalize later
      bfr[sj] = *(s16x8*)tmp;
    }
    #pragma unroll
    for (int ot = 0; ot < 4; ot++)
      #pragma unroll
      for (int sj = 0; sj < 2; sj++)
        acc[ot][sj] = __builtin_amdgcn_mfma_f32_16x16x32_bf16(af[ot], bfr[sj], acc[ot][sj], 0, 0, 0);
  }

  #pragma unroll
  for (int ot = 0; ot < 4; ot++) {
    #pragma unroll
    for (int r = 0; r < 4; r++) {
      int o = obase + ot * 16 + lg * 4 + r;
      float bi = bias[o];
      #pragma unroll
      for (int sj = 0; sj < 2; sj++) {
        int s = sbase + sj * 16 + l15;
        size_t idx = ((size_t)b * CCH + o) * SEQ + s;
        out[idx] = acc[ot][sj][r] * inv[sj] + bi + x[idx];
      }
    }
  }
}

extern "C" void kernel_launch(void* const* d_in, const int* in_sizes, int n_in,
                              void* d_out, int out_size, void* d_ws, size_t ws_size,
                              hipStream_t stream) {
  const float* x     = (const float*)d_in[0];
  const float* w_qkv = (const float*)d_in[1];
  const float* b_qkv = (const float*)d_in[2];
  const float* w_out = (const float*)d_in[3];
  const float* b_out = (const float*)d_in[4];
  float* out = (float*)d_out;

  // ws: qb 0 | kb 8 | vb 16 | wqkb 24 | wob 24.5 | llp 25 | pacc 26.. (split4 ends 59.6)
  char* ws = (char*)d_ws;
  unsigned short* qbp  = (unsigned short*)(ws);
  unsigned short* kbp  = (unsigned short*)(ws + ((size_t)8 << 20));
  unsigned short* vbp  = (unsigned short*)(ws + ((size_t)16 << 20));
  unsigned short* wqkb = (unsigned short*)(ws + ((size_t)24 << 20));
  unsigned short* wob  = (unsigned short*)(ws + ((size_t)24 << 20) + (512u << 10));
  float*          llp  = (float*)(ws + ((size_t)25 << 20));
  __half*         pacc = (__half*)(ws + ((size_t)26 << 20));

  prep<<<dim3(256), 256, 0, stream>>>(w_qkv, w_out, wqkb, wob);
  qkv_proj<<<dim3(128, NB), 512, 0, stream>>>(x, wqkb, b_qkv, qbp, kbp, vbp);

  bool split4 = ws_size >= ((size_t)60 << 20);
  if (split4) {
    attn_kernel<4><<<dim3(16, 4, NB), 512, 0, stream>>>(qbp, kbp, vbp, pacc, llp);
    out_proj<4><<<dim3(128, NB), 256, 0, stream>>>(pacc, llp, wob, b_out, x, out);
  } else {
    attn_kernel<2><<<dim3(16, 2, NB), 512, 0, stream>>>(qbp, kbp, vbp, pacc, llp);
    out_proj<2><<<dim3(128, NB), 256, 0, stream>>>(pacc, llp, wob, b_out, x, out);
  }
}

// Round 14
// 149.179 us; speedup vs baseline: 1.0451x; 1.0098x over previous
//
#include <hip/hip_runtime.h>
#include <hip/hip_bf16.h>
#include <hip/hip_fp16.h>
#include <math.h>

typedef short s16x8 __attribute__((ext_vector_type(8)));
typedef float f32x4 __attribute__((ext_vector_type(4)));
typedef float f32x16 __attribute__((ext_vector_type(16)));
typedef unsigned short u16x4 __attribute__((ext_vector_type(4)));
typedef unsigned short u16x8 __attribute__((ext_vector_type(8)));
typedef unsigned int u32x4 __attribute__((ext_vector_type(4)));

#define CCH 256
#define SEQ 4096
#define NB 4
#define KVB 64

static __device__ __forceinline__ unsigned short f2bf(float f) {
  union { float f; unsigned int u; } v; v.f = f;
  unsigned int u = v.u;
  unsigned int r = u + 0x7FFFu + ((u >> 16) & 1u);   // RNE
  return (unsigned short)(r >> 16);
}

static __device__ __forceinline__ void gl16(const void* g, void* l) {
  __builtin_amdgcn_global_load_lds(
      (const __attribute__((address_space(1))) void*)g,
      (__attribute__((address_space(3))) void*)l, 16, 0, 0);
}

static __device__ __forceinline__ unsigned int cvt_pk_bf16(float lo, float hi) {
  unsigned int w;
  asm("v_cvt_pk_bf16_f32 %0, %1, %2" : "=v"(w) : "v"(lo), "v"(hi));
  return w;
}

// ---------------- prep: weight matrices fp32 -> bf16 only ----------------
__global__ __launch_bounds__(256) void prep(
    const float* __restrict__ wqkv, const float* __restrict__ wout,
    unsigned short* __restrict__ wqkb, unsigned short* __restrict__ wob)
{
  int bid = blockIdx.x;
  int tid = threadIdx.x;
  const float* src; unsigned short* dst; int i;
  if (bid < 192) { src = wqkv; dst = wqkb; i = bid * 256 + tid; }
  else           { src = wout; dst = wob;  i = (bid - 192) * 256 + tid; }
  float4 v = ((const float4*)src)[i];
  u16x4 r;
  r.x = f2bf(v.x); r.y = f2bf(v.y); r.z = f2bf(v.z); r.w = f2bf(v.w);
  ((u16x4*)dst)[i] = r;
}

// ---------------- qkv_proj: balanced 8-wave split, each wave 96 of 768 out-rows ------
// Per 16-row tile: m = orow>>8 (0=q 1=k 2=v). q/k: D[s][o] = mfma(af, wf).
// v: D[o][s] = mfma(wf, af) -> vb[c][s]. Same af registers both ways.
__global__ __launch_bounds__(512) void qkv_proj(
    const float* __restrict__ x, const unsigned short* __restrict__ wqkb,
    const float* __restrict__ bias,
    unsigned short* __restrict__ qb, unsigned short* __restrict__ kb,
    unsigned short* __restrict__ vb)
{
  __shared__ __align__(16) unsigned short T[32][256];   // 16KB, chunk c16 ^= (s&7)
  int b = blockIdx.y, st = blockIdx.x;   // st 0..127
  int tid = threadIdx.x, w = tid >> 6, l = tid & 63, l15 = l & 15, lg = l >> 4;
  int sbase = st * 32;
  int s7 = l15 & 7;

  #pragma unroll
  for (int i = 0; i < 4; i++) {
    int idx = i * 512 + tid;
    int sc = idx & 7, ch = idx >> 3;
    float4 v = *(const float4*)&x[((size_t)b * CCH + ch) * SEQ + sbase + sc * 4];
    #pragma unroll
    for (int j = 0; j < 4; j++) {
      int s = sc * 4 + j;
      int csw = (((ch >> 3) ^ (s & 7)) << 3) | (ch & 7);
      float fv = (j == 0) ? v.x : (j == 1) ? v.y : (j == 2) ? v.z : v.w;
      T[s][csw] = f2bf(fv);
    }
  }
  __syncthreads();

  // x fragments for both 16-row halves of this block's 32 s-rows
  s16x8 af[2][8];
  #pragma unroll
  for (int sj = 0; sj < 2; sj++)
    #pragma unroll
    for (int t = 0; t < 8; t++)
      af[sj][t] = *(const s16x8*)&T[sj * 16 + l15][(((t * 4 + lg) ^ s7)) * 8];

  #pragma unroll
  for (int tI = 0; tI < 6; tI++) {
    int orow = w * 96 + tI * 16;
    int m = orow >> 8;            // 0=q 1=k 2=v
    int ch0 = orow & 255;
    f32x4 acc[2];
    acc[0] = (f32x4){0.f, 0.f, 0.f, 0.f};
    acc[1] = (f32x4){0.f, 0.f, 0.f, 0.f};
    if (m < 2) {
      #pragma unroll
      for (int kt = 0; kt < 8; kt++) {
        s16x8 wf = *(const s16x8*)&wqkb[(size_t)(orow + l15) * CCH + kt * 32 + lg * 8];
        acc[0] = __builtin_amdgcn_mfma_f32_16x16x32_bf16(af[0][kt], wf, acc[0], 0, 0, 0);
        acc[1] = __builtin_amdgcn_mfma_f32_16x16x32_bf16(af[1][kt], wf, acc[1], 0, 0, 0);
      }
      unsigned short* dst = m ? kb : qb;
      float bi = bias[orow + l15];
      int ch = ch0 + l15;
      #pragma unroll
      for (int sj = 0; sj < 2; sj++)
        #pragma unroll
        for (int r = 0; r < 4; r++) {
          int srow = sbase + sj * 16 + lg * 4 + r;
          dst[((size_t)b * SEQ + srow) * CCH + ch] = f2bf(acc[sj][r] + bi);
        }
    } else {
      #pragma unroll
      for (int kt = 0; kt < 8; kt++) {
        s16x8 wf = *(const s16x8*)&wqkb[(size_t)(orow + l15) * CCH + kt * 32 + lg * 8];
        acc[0] = __builtin_amdgcn_mfma_f32_16x16x32_bf16(wf, af[0][kt], acc[0], 0, 0, 0);
        acc[1] = __builtin_amdgcn_mfma_f32_16x16x32_bf16(wf, af[1][kt], acc[1], 0, 0, 0);
      }
      #pragma unroll
      for (int r = 0; r < 4; r++) {
        int o = ch0 + lg * 4 + r;
        float bi = bias[512 + o];
        #pragma unroll
        for (int sj = 0; sj < 2; sj++) {
          int s = sbase + sj * 16 + l15;
          vb[((size_t)b * CCH + o) * SEQ + s] = f2bf(acc[sj][r] + bi);
        }
      }
    }
  }
}

// ---------------- attn: 32x32x16, KVB=64, in-reg P (round-10/13 proven, UNCHANGED) ----
template<int NSPLIT_>
__global__ __launch_bounds__(512, 2) void attn_kernel(
    const unsigned short* __restrict__ qb,
    const unsigned short* __restrict__ kb,
    const unsigned short* __restrict__ vb,
    __half* __restrict__ pacc, float* __restrict__ llp)
{
  constexpr int KVLEN_ = SEQ / NSPLIT_;
  constexpr int NT_ = KVLEN_ / KVB;
  __shared__ __align__(16) unsigned short Ks[2][KVB * CCH];   // 2 x 32KB
  __shared__ __align__(16) unsigned short Vs[2][CCH * KVB];   // 2 x 32KB

  int b = blockIdx.z, kvh = blockIdx.y, qt = blockIdx.x;
  int tid = threadIdx.x, w = tid >> 6, l = tid & 63;
  int l31 = l & 31, lh = l >> 5;
  int s7 = l31 & 7;

  int qrow0 = qt * 256 + w * 32;
  const unsigned short* qptr = qb + ((size_t)b * SEQ + qrow0 + l31) * CCH + lh * 8;
  s16x8 qf[16];
  #pragma unroll
  for (int t = 0; t < 16; t++) qf[t] = *(const s16x8*)(qptr + t * 16);

  f32x16 oacc[8];
  #pragma unroll
  for (int i = 0; i < 8; i++)
    #pragma unroll
    for (int j = 0; j < 16; j++) oacc[i][j] = 0.f;
  float ll = 0.f;

  int koff0 = (tid >> 5) * CCH + (((tid & 31) ^ ((tid >> 5) & 7)) * 8);
  int voff0 = (tid >> 3) * SEQ + (((tid & 7) ^ ((tid >> 3) & 7)) * 8);
  const unsigned short* kbb = kb + (size_t)b * SEQ * CCH + (size_t)kvh * KVLEN_ * CCH;
  const unsigned short* vbb = vb + (size_t)b * CCH * SEQ + kvh * KVLEN_;

  auto stage = [&](int bf_, int kv) {
    #pragma unroll
    for (int i = 0; i < 4; i++)
      gl16(kbb + (size_t)kv * KVB * CCH + koff0 + i * 16 * CCH, &Ks[bf_][(i * 512 + tid) * 8]);
    #pragma unroll
    for (int i = 0; i < 4; i++)
      gl16(vbb + kv * KVB + voff0 + (size_t)i * 64 * SEQ, &Vs[bf_][(i * 512 + tid) * 8]);
  };

  stage(0, 0);
  __syncthreads();

  int buf = 0;
  for (int kv = 0; kv < NT_; kv++) {
    if (kv + 1 < NT_) stage(buf ^ 1, kv + 1);

    #pragma unroll
    for (int h = 0; h < 2; h++) {
      f32x16 sacc;
      #pragma unroll
      for (int i = 0; i < 16; i++) sacc[i] = 0.f;
      __builtin_amdgcn_s_setprio(1);
      #pragma unroll
      for (int st = 0; st < 16; st++) {
        s16x8 kf = *(const s16x8*)&Ks[buf][(h * 32 + l31) * CCH + (((st * 2 + lh) ^ s7) * 8)];
        sacc = __builtin_amdgcn_mfma_f32_32x32x16_bf16(kf, qf[st], sacc, 0, 0, 0);
      }
      __builtin_amdgcn_s_setprio(0);

      unsigned int pw[8];
      #pragma unroll
      for (int r = 0; r < 8; r++) {
        float p0 = __builtin_amdgcn_exp2f(fmaf(sacc[2 * r],     0.09016844f, -11.5415602f));
        float p1 = __builtin_amdgcn_exp2f(fmaf(sacc[2 * r + 1], 0.09016844f, -11.5415602f));
        ll += p0 + p1;
        pw[r] = cvt_pk_bf16(p0, p1);
      }
      asm volatile("v_permlane32_swap_b32 %0, %1" : "+v"(pw[0]), "+v"(pw[2]));
      asm volatile("v_permlane32_swap_b32 %0, %1" : "+v"(pw[1]), "+v"(pw[3]));
      asm volatile("v_permlane32_swap_b32 %0, %1" : "+v"(pw[4]), "+v"(pw[6]));
      asm volatile("v_permlane32_swap_b32 %0, %1" : "+v"(pw[5]), "+v"(pw[7]));
      u32x4 pa0u = {pw[0], pw[1], pw[2], pw[3]};   // keys h*32 + 0..15
      u32x4 pa1u = {pw[4], pw[5], pw[6], pw[7]};   // keys h*32 + 16..31
      s16x8 pa0 = *(s16x8*)&pa0u;
      s16x8 pa1 = *(s16x8*)&pa1u;

      __builtin_amdgcn_s_setprio(1);
      #pragma unroll
      for (int dt = 0; dt < 8; dt++) {
        int base = (dt * 32 + l31) * KVB;
        s16x8 vf0 = *(const s16x8*)&Vs[buf][base + (((h * 4 + lh) ^ s7) * 8)];
        oacc[dt] = __builtin_amdgcn_mfma_f32_32x32x16_bf16(pa0, vf0, oacc[dt], 0, 0, 0);
        s16x8 vf1 = *(const s16x8*)&Vs[buf][base + (((h * 4 + 2 + lh) ^ s7) * 8)];
        oacc[dt] = __builtin_amdgcn_mfma_f32_32x32x16_bf16(pa1, vf1, oacc[dt], 0, 0, 0);
      }
      __builtin_amdgcn_s_setprio(0);
    }

    __syncthreads();
    buf ^= 1;
  }

  ll += __shfl_xor(ll, 32);
  size_t pbase = (size_t)(b * NSPLIT_ + kvh) * SEQ;
  if (lh == 0) llp[pbase + qrow0 + l31] = ll;
  __half* pb_ = pacc + (pbase + qrow0) * CCH + l31;
  #pragma unroll
  for (int rg = 0; rg < 4; rg++)
    #pragma unroll
    for (int j = 0; j < 4; j++) {
      int qr = j + 8 * rg + 4 * lh;
      #pragma unroll
      for (int dt = 0; dt < 8; dt++)
        pb_[(size_t)qr * CCH + dt * 32] = __float2half(oacc[dt][rg * 4 + j]);
    }
}

// ---------------- out_proj: s-tile 16 (grid x2 = 4 blocks/CU), deferred norm ----------
template<int NS>
__global__ __launch_bounds__(256) void out_proj(
    const __half* __restrict__ pacc, const float* __restrict__ llp,
    const unsigned short* __restrict__ wb,
    const float* __restrict__ bias, const float* __restrict__ x,
    float* __restrict__ out)
{
  int b = blockIdx.y, st = blockIdx.x;   // st 0..255
  int tid = threadIdx.x, w = tid >> 6, l = tid & 63, l15 = l & 15, lg = l >> 4;
  int sbase = st * 16, obase = w * 64;
  int s = sbase + l15;

  float den = 0.f;
  #pragma unroll
  for (int k = 0; k < NS; k++) den += llp[(size_t)(b * NS + k) * SEQ + s];
  float inv = 1.f / den;

  f32x4 acc[4];
  #pragma unroll
  for (int i = 0; i < 4; i++) acc[i] = (f32x4){0.f, 0.f, 0.f, 0.f};

  #pragma unroll
  for (int kt = 0; kt < 8; kt++) {
    s16x8 af[4], bfr;
    #pragma unroll
    for (int ot = 0; ot < 4; ot++)
      af[ot] = *(const s16x8*)&wb[(obase + ot * 16 + l15) * CCH + kt * 32 + lg * 8];
    float facc[8] = {0.f, 0.f, 0.f, 0.f, 0.f, 0.f, 0.f, 0.f};
    #pragma unroll
    for (int k = 0; k < NS; k++) {
      const __half* p = pacc + ((size_t)(b * NS + k) * SEQ + s) * CCH + kt * 32 + lg * 8;
      u16x8 h8 = *(const u16x8*)(p);
      #pragma unroll
      for (int j = 0; j < 8; j++)
        facc[j] += __half2float(*(const __half*)&((const unsigned short*)&h8)[j]);
    }
    unsigned short tmp[8];
    #pragma unroll
    for (int j = 0; j < 8; j++) tmp[j] = f2bf(facc[j]);   // raw sums; normalize later
    bfr = *(s16x8*)tmp;
    #pragma unroll
    for (int ot = 0; ot < 4; ot++)
      acc[ot] = __builtin_amdgcn_mfma_f32_16x16x32_bf16(af[ot], bfr, acc[ot], 0, 0, 0);
  }

  #pragma unroll
  for (int ot = 0; ot < 4; ot++) {
    #pragma unroll
    for (int r = 0; r < 4; r++) {
      int o = obase + ot * 16 + lg * 4 + r;
      float bi = bias[o];
      size_t idx = ((size_t)b * CCH + o) * SEQ + s;
      out[idx] = acc[ot][r] * inv + bi + x[idx];
    }
  }
}

extern "C" void kernel_launch(void* const* d_in, const int* in_sizes, int n_in,
                              void* d_out, int out_size, void* d_ws, size_t ws_size,
                              hipStream_t stream) {
  const float* x     = (const float*)d_in[0];
  const float* w_qkv = (const float*)d_in[1];
  const float* b_qkv = (const float*)d_in[2];
  const float* w_out = (const float*)d_in[3];
  const float* b_out = (const float*)d_in[4];
  float* out = (float*)d_out;

  // ws: qb 0 | kb 8 | vb 16 | wqkb 24 | wob 24.5 | llp 25 | pacc 26.. (split4 ends 59.6)
  char* ws = (char*)d_ws;
  unsigned short* qbp  = (unsigned short*)(ws);
  unsigned short* kbp  = (unsigned short*)(ws + ((size_t)8 << 20));
  unsigned short* vbp  = (unsigned short*)(ws + ((size_t)16 << 20));
  unsigned short* wqkb = (unsigned short*)(ws + ((size_t)24 << 20));
  unsigned short* wob  = (unsigned short*)(ws + ((size_t)24 << 20) + (512u << 10));
  float*          llp  = (float*)(ws + ((size_t)25 << 20));
  __half*         pacc = (__half*)(ws + ((size_t)26 << 20));

  prep<<<dim3(256), 256, 0, stream>>>(w_qkv, w_out, wqkb, wob);
  qkv_proj<<<dim3(128, NB), 512, 0, stream>>>(x, wqkb, b_qkv, qbp, kbp, vbp);

  bool split4 = ws_size >= ((size_t)60 << 20);
  if (split4) {
    attn_kernel<4><<<dim3(16, 4, NB), 512, 0, stream>>>(qbp, kbp, vbp, pacc, llp);
    out_proj<4><<<dim3(256, NB), 256, 0, stream>>>(pacc, llp, wob, b_out, x, out);
  } else {
    attn_kernel<2><<<dim3(16, 2, NB), 512, 0, stream>>>(qbp, kbp, vbp, pacc, llp);
    out_proj<2><<<dim3(256, NB), 256, 0, stream>>>(pacc, llp, wob, b_out, x, out);
  }
}